// Round 18
// baseline (31.788 us; speedup 1.0000x reference)
//
#include <hip/hip_runtime.h>
#include <hip/hip_fp16.h>
#include <math.h>

#define W 384
#define H 384
#define NB 32
#define NPIX (W*H)

#define BAND 16
#define NBANDS (H/BAND)            // 24
#define NBLK1 (NB*NBANDS)          // 768 blocks = 3/CU exactly
#define LSTR 416                   // 16 zero pad | 384 | 16 replicate pad

#define NBLK2 1536                 // K2: 256 thr, 4 waves; 48 blocks/img
#define CGPI 48                    // chunk-groups (blocks) per image
#define ITERS 3                    // 3 x 256 px per wave = 768 px (2 rows) per wave

// partials layout: SoA, 5 planes of NBLK2 floats.

// ---------------------------------------------------------------------------
// K1: per 16-row band: row-prefix -> band 2D prefix S (LDS, reg-chained) ->
// V_k[y][x] = S[y][x+k] - S[y][x-k-1]  (fp16, horizontal clamps via pads)
// ---------------------------------------------------------------------------
__global__ __launch_bounds__(384) void band_v_kernel(
    const float* __restrict__ mask,
    __half* __restrict__ V3, __half* __restrict__ V15, __half* __restrict__ V31)
{
    __shared__ float lds[BAND][LSTR];     // 26,624 B

    const int tid  = threadIdx.x;
    const int wave = tid >> 6;
    const int lane = tid & 63;
    const int bid  = blockIdx.x;
    const int b    = (bid & 7) + 8 * ((bid >> 3) / NBANDS);   // img%8 == XCD
    const int band = (bid >> 3) % NBANDS;
    const int y0   = band * BAND;

    const float* mimg = mask + (size_t)b * NPIX;

    // phase 0: zero the 16-col left pads (16 rows x 16 = 256 slots)
    if (tid < 256) { lds[tid >> 4][tid & 15] = 0.0f; }

    // phase 1: row prefix of each band row into lds[r][16..399]
    {
        const int x0 = lane * 6;
        #pragma unroll
        for (int i = 0; i < 3; ++i) {
            const int r = wave + i * 6;
            if (r < BAND) {
                const float2* src = (const float2*)(mimg + (size_t)(y0 + r) * W + x0);
                const float2 q0 = src[0], q1 = src[1], q2 = src[2];
                const float s0 = q0.x;
                const float s1 = s0 + q0.y;
                const float s2 = s1 + q1.x;
                const float s3 = s2 + q1.y;
                const float s4 = s3 + q2.x;
                const float s5 = s4 + q2.y;
                float ss = s5;
                #pragma unroll
                for (int d = 1; d < 64; d <<= 1) {
                    float t = __shfl_up(ss, d);
                    if (lane >= d) ss += t;
                }
                const float base = ss - s5;
                float2* dst = (float2*)&lds[r][16 + x0];
                dst[0] = make_float2(base + s0, base + s1);
                dst[1] = make_float2(base + s2, base + s3);
                dst[2] = make_float2(base + s4, base + s5);
            }
        }
    }
    __syncthreads();

    // phase 2: column prefix via registers (independent reads, reg chain)
    {
        const int c = 16 + tid;            // tid in [0,384): every column
        float v[BAND];
        #pragma unroll
        for (int r = 0; r < BAND; ++r) v[r] = lds[r][c];
        float acc = 0.0f;
        #pragma unroll
        for (int r = 0; r < BAND; ++r) { acc += v[r]; v[r] = acc; }
        #pragma unroll
        for (int r = 0; r < BAND; ++r) lds[r][c] = v[r];
    }
    __syncthreads();

    // phase 3: right pads = S[r][383] (col 399) replicated to cols 400..415
    if (tid < 256) {
        const int r = tid >> 4, j = tid & 15;
        lds[r][400 + j] = lds[r][399];
    }
    __syncthreads();

    // phase 4: V taps + half2 store. thread -> (col pair, row half)
    {
        const int cp = tid % 192;          // col pair: cols 2cp, 2cp+1
        const int hf = tid / 192;          // rows hf*8 .. hf*8+7
        const int c0 = 16 + 2 * cp;
        const size_t obase = (size_t)b * NPIX + (size_t)y0 * W + 2 * cp;
        #pragma unroll
        for (int rr = 0; rr < 8; ++rr) {
            const int r = hf * 8 + rr;
            const float* R = lds[r];
            const __half2 h3  = __floats2half2_rn(R[c0+1]  - R[c0-2],  R[c0+2]  - R[c0-1]);
            const __half2 h15 = __floats2half2_rn(R[c0+7]  - R[c0-8],  R[c0+8]  - R[c0-7]);
            const __half2 h31 = __floats2half2_rn(R[c0+15] - R[c0-16], R[c0+16] - R[c0-15]);
            const size_t o = obase + (size_t)r * W;
            *(__half2*)(V3  + o) = h3;
            *(__half2*)(V15 + o) = h15;
            *(__half2*)(V31 + o) = h31;
        }
    }
}

// ---------------------------------------------------------------------------
// K2: fused loss. 4 cols/lane. Band-total taps (AT, BT, T2) are now
// CONDITIONAL: zero-init + exec-masked load only when the window actually
// crosses a band boundary (AT ~12%, BT ~50%, T2 ~6% of rows). Saves ~16%
// of line traffic vs branchless flag-multiplies that always fetch.
// ---------------------------------------------------------------------------
struct __align__(8) H4 { __half2 a, b; };

__device__ inline void h4f(const H4 h, float o[4]) {
    const float2 fa = __half22float2(h.a);
    const float2 fb = __half22float2(h.b);
    o[0] = fa.x; o[1] = fa.y; o[2] = fb.x; o[3] = fb.y;
}

__global__ __launch_bounds__(256) void loss_kernel(
    const float* __restrict__ pred, const float* __restrict__ mask,
    const __half* __restrict__ V3, const __half* __restrict__ V15,
    const __half* __restrict__ V31, float* __restrict__ partials)
{
    const int tid  = threadIdx.x;
    const int wave = tid >> 6;
    const int lane = tid & 63;
    const int bid  = blockIdx.x;
    const int j    = bid >> 3;                    // 0..191
    const int b    = (bid & 7) + 8 * (j / CGPI);  // img%8 == XCD
    const int cg   = j % CGPI;                    // 0..47
    const int chunk = cg * 4 + wave;              // rows [2*chunk, 2*chunk+2)

    const size_t ibase = (size_t)b * NPIX;
    const float* mimg = mask + ibase;
    const float* pimg = pred + ibase;

    float pw = 0.f, pin = 0.f, pun = 0.f, pb = 0.f, pm = 0.f;
    // 0.5 folded into the box reciprocals (|b*k - m|*0.5 == |b*(k/2) - m/2|)
    const float i9h = 0.5f/9.0f, i225h = 0.5f/225.0f, i961h = 0.5f/961.0f;

    #pragma unroll
    for (int it = 0; it < ITERS; ++it) {
        const int q  = it * 256 + (lane << 2);    // 0..764
        const int yo = (q >= 384) ? 1 : 0;
        const int y  = (chunk << 1) + yo;
        const int x  = q - (yo ? 384 : 0);        // multiple of 4
        const size_t po = (size_t)chunk * 768 + q;

        const __half* v3x  = V3  + ibase + x;
        const __half* v15x = V15 + ibase + x;
        const __half* v31x = V31 + ibase + x;

        // ---- addresses & flags -------------------------------------------
        const int y1a  = min(y + 1, H - 1);
        const int yloa = y - 2;
        const int y0a  = yloa < 0 ? 0 : yloa;
        const int yta  = y0a | (BAND - 1);
        const float fLoA = yloa >= 0 ? 1.0f : 0.0f;
        const bool  cA   = (yloa >= 0) && ((y0a >> 4) != (y1a >> 4));

        const int y1b  = min(y + 7, H - 1);
        const int ylob = y - 8;
        const int y0b  = ylob < 0 ? 0 : ylob;
        const int ytb  = y0b | (BAND - 1);
        const float fLoB = ylob >= 0 ? 1.0f : 0.0f;
        const bool  cB   = (ylob >= 0) && ((y0b >> 4) != (y1b >> 4));

        const int y1c  = min(y + 15, H - 1);
        const int yloc = y - 16;
        const int y0c  = yloc < 0 ? 0 : yloc;
        const int sc   = yloc >= 0 ? (y0c >> 4) : 0;
        const int nc   = (y1c >> 4) - sc;
        const int rt1  = sc * BAND + (BAND - 1);
        const int rt2  = min(rt1 + BAND, H - 1);
        const float fLoC = yloc >= 0 ? 1.0f : 0.0f;
        const float g1   = nc >= 1 ? 1.0f : 0.0f;
        const bool  cT2  = (nc >= 2);

        // ---- loads (crossing taps conditional) ---------------------------
        const H4 A1 = *(const H4*)(v3x  + (size_t)y1a * W);
        const H4 A0 = *(const H4*)(v3x  + (size_t)y0a * W);
        const H4 B1 = *(const H4*)(v15x + (size_t)y1b * W);
        const H4 B0 = *(const H4*)(v15x + (size_t)y0b * W);
        const H4 C1 = *(const H4*)(v31x + (size_t)y1c * W);
        const H4 C0 = *(const H4*)(v31x + (size_t)y0c * W);
        const H4 T1 = *(const H4*)(v31x + (size_t)rt1 * W);
        const float4 mv = *(const float4*)(mimg + po);
        const float4 pv = *(const float4*)(pimg + po);

        float at[4] = {0.f, 0.f, 0.f, 0.f};
        float bt[4] = {0.f, 0.f, 0.f, 0.f};
        float t2[4] = {0.f, 0.f, 0.f, 0.f};
        if (cA)  { const H4 AT = *(const H4*)(v3x  + (size_t)yta * W); h4f(AT, at); }
        if (cB)  { const H4 BT = *(const H4*)(v15x + (size_t)ytb * W); h4f(BT, bt); }
        if (cT2) { const H4 T2 = *(const H4*)(v31x + (size_t)rt2 * W); h4f(T2, t2); }

        // ---- convert + combine + loss ------------------------------------
        float a1[4], a0[4], b1[4], b0[4], c1[4], c0[4], t1[4];
        h4f(A1, a1); h4f(A0, a0);
        h4f(B1, b1); h4f(B0, b0);
        h4f(C1, c1); h4f(C0, c0); h4f(T1, t1);

        const float mm[4] = { mv.x, mv.y, mv.z, mv.w };
        const float pp[4] = { pv.x, pv.y, pv.z, pv.w };

        #pragma unroll
        for (int c = 0; c < 4; ++c) {
            const float b3v  = a1[c] - fLoA * a0[c] + at[c];
            const float b15v = b1[c] - fLoB * b0[c] + bt[c];
            const float b31v = c1[c] - fLoC * c0[c] + g1 * t1[c] + t2[c];

            const float m = mm[c], p = pp[c];
            const float hm = 0.5f * m;
            const float t3  = fmaf(b3v,  i9h,   -hm);
            const float t15 = fmaf(b15v, i225h, -hm);
            const float t31 = fmaf(b31v, i961h, -hm);
            const float wh  = fabsf(t3) + fabsf(t15) + fabsf(t31);  // 0.5*w
            const float weit = fmaf(wh, m, 1.0f);                   // 1 + 0.5*w*m
            pw  += weit;
            pin  = fmaf(p * m, weit, pin);
            pun  = fmaf(p + m, weit, pun);
            const float lp = __log2f(p);
            const float lq = __log2f(1.0f - p);
            pb  -= fmaf(m, lp - lq, lq);     // = m*log2(p) + (1-m)*log2(1-p)
            pm  += fabsf(p - m);
        }
    }

    // deterministic wave butterfly
    #pragma unroll
    for (int off = 32; off >= 1; off >>= 1) {
        pw  += __shfl_xor(pw,  off);
        pin += __shfl_xor(pin, off);
        pun += __shfl_xor(pun, off);
        pb  += __shfl_xor(pb,  off);
        pm  += __shfl_xor(pm,  off);
    }
    __shared__ float red[4][5];
    if (lane == 0) {
        red[wave][0]=pw; red[wave][1]=pin; red[wave][2]=pun; red[wave][3]=pb; red[wave][4]=pm;
    }
    __syncthreads();
    if (tid == 0) {
        const int idx = b * CGPI + cg;               // 0..1535
        partials[0*NBLK2 + idx] = red[0][0]+red[1][0]+red[2][0]+red[3][0];
        partials[1*NBLK2 + idx] = red[0][1]+red[1][1]+red[2][1]+red[3][1];
        partials[2*NBLK2 + idx] = red[0][2]+red[1][2]+red[2][2]+red[3][2];
        partials[3*NBLK2 + idx] = red[0][3]+red[1][3]+red[2][3]+red[3][3];
        partials[4*NBLK2 + idx] = red[0][4]+red[1][4]+red[2][4]+red[3][4];
    }
}

// ---------------------------------------------------------------------------
// K3: finalize. 256 threads, fp64, fixed order -> deterministic scalar.
// SoA partials -> lane-coalesced loads.
// ---------------------------------------------------------------------------
__global__ __launch_bounds__(256) void finalize_kernel(
    const float* __restrict__ partials, float* __restrict__ out)
{
    __shared__ double sB[4], sM[4];
    __shared__ double sw_[NB], si_[NB], su_[NB];

    const int tid = threadIdx.x;
    const int i   = tid >> 3;                 // image 0..31
    const int s   = tid & 7;

    // global bce/mae sums: fully coalesced (plane 3 and 4)
    double Bc = 0, Ma = 0;
    #pragma unroll
    for (int jj = 0; jj < NBLK2 / 256; ++jj) {
        Bc += (double)partials[3*NBLK2 + tid + 256*jj];
        Ma += (double)partials[4*NBLK2 + tid + 256*jj];
    }
    // per-image sums: 8 lanes per image, consecutive k within group
    double Sw = 0, Si = 0, Su = 0;
    #pragma unroll
    for (int jj = 0; jj < CGPI / 8; ++jj) {
        const int k = i * CGPI + s + 8*jj;
        Sw += (double)partials[0*NBLK2 + k];
        Si += (double)partials[1*NBLK2 + k];
        Su += (double)partials[2*NBLK2 + k];
    }
    #pragma unroll
    for (int d = 4; d >= 1; d >>= 1) {
        Sw += __shfl_down(Sw, d);
        Si += __shfl_down(Si, d);
        Su += __shfl_down(Su, d);
    }
    if (s == 0) { sw_[i] = Sw; si_[i] = Si; su_[i] = Su; }
    #pragma unroll
    for (int d = 32; d >= 1; d >>= 1) {
        Bc += __shfl_down(Bc, d);
        Ma += __shfl_down(Ma, d);
    }
    if ((tid & 63) == 0) { sB[tid >> 6] = Bc; sM[tid >> 6] = Ma; }
    __syncthreads();

    if (tid < 64) {
        double wiou = 0.0, ratio = 0.0;
        if (tid < NB) {
            const double w = sw_[tid], ii = si_[tid], u = su_[tid];
            wiou  = 1.0 - ii / (u - ii);
            ratio = w / (w - (double)NPIX);
        }
        #pragma unroll
        for (int d = 32; d >= 1; d >>= 1) {
            wiou  += __shfl_down(wiou,  d);
            ratio += __shfl_down(ratio, d);
        }
        if (tid == 0) {
            const double bt  = (sB[0] + sB[1] + sB[2] + sB[3]) * 0.6931471805599453; // ln2
            const double mt  = sM[0] + sM[1] + sM[2] + sM[3];
            const double tot = (double)NB * (double)NPIX;
            const double bce = bt / tot;
            const double mae = mt / tot;
            out[0] = (float)(0.7 * (bce + wiou / (double)NB + mae * ratio / (double)NB));
        }
    }
}

extern "C" void kernel_launch(void* const* d_in, const int* in_sizes, int n_in,
                              void* d_out, int out_size, void* d_ws, size_t ws_size,
                              hipStream_t stream) {
    const float* pred = (const float*)d_in[0];
    const float* mask = (const float*)d_in[1];
    float* out        = (float*)d_out;

    // ws layout: V3 | V15 | V31 (each 32*384*384 fp16 = 4.72 MB) | partials(SoA)
    const size_t vplane = (size_t)NB * NPIX;           // elements
    __half* V3  = (__half*)d_ws;
    __half* V15 = V3  + vplane;
    __half* V31 = V15 + vplane;
    float* partials = (float*)(V31 + vplane);          // 5*1536*4 = 30 KB

    band_v_kernel<<<dim3(NBLK1), dim3(384), 0, stream>>>(mask, V3, V15, V31);
    loss_kernel<<<dim3(NBLK2), dim3(256), 0, stream>>>(pred, mask, V3, V15, V31, partials);
    finalize_kernel<<<dim3(1), dim3(256), 0, stream>>>(partials, out);
}

// Round 19
// 28.875 us; speedup vs baseline: 1.1009x; 1.1009x over previous
//
#include <hip/hip_runtime.h>
#include <hip/hip_fp16.h>
#include <math.h>

#define W 384
#define H 384
#define NB 32
#define NPIX (W*H)

#define BAND 16
#define NBANDS (H/BAND)            // 24
#define NBLK1 (NB*NBANDS)          // 768 blocks = 3/CU exactly
#define LSTR 416                   // 16 zero pad | 384 | 16 replicate pad

#define NBLK2 1536                 // K2: 256 thr, 4 waves; 48 blocks/img
#define CGPI 48                    // chunk-groups (blocks) per image
#define ITERS 3                    // 3 x 256 px per wave = 768 px (2 rows) per wave

// partials layout: SoA, 5 planes of NBLK2 floats (plane q at q*NBLK2 + idx).

// ---------------------------------------------------------------------------
// K1: per 16-row band: row-prefix -> band 2D prefix S (LDS, reg-chained) ->
// V_k[y][x] = S[y][x+k] - S[y][x-k-1]  (fp16, horizontal clamps via pads)
// ---------------------------------------------------------------------------
__global__ __launch_bounds__(384) void band_v_kernel(
    const float* __restrict__ mask,
    __half* __restrict__ V3, __half* __restrict__ V15, __half* __restrict__ V31)
{
    __shared__ float lds[BAND][LSTR];     // 26,624 B

    const int tid  = threadIdx.x;
    const int wave = tid >> 6;
    const int lane = tid & 63;
    const int bid  = blockIdx.x;
    const int b    = (bid & 7) + 8 * ((bid >> 3) / NBANDS);   // img%8 == XCD
    const int band = (bid >> 3) % NBANDS;
    const int y0   = band * BAND;

    const float* mimg = mask + (size_t)b * NPIX;

    // phase 0: zero the 16-col left pads (16 rows x 16 = 256 slots)
    if (tid < 256) { lds[tid >> 4][tid & 15] = 0.0f; }

    // phase 1: row prefix of each band row into lds[r][16..399]
    {
        const int x0 = lane * 6;
        #pragma unroll
        for (int i = 0; i < 3; ++i) {
            const int r = wave + i * 6;
            if (r < BAND) {
                const float2* src = (const float2*)(mimg + (size_t)(y0 + r) * W + x0);
                const float2 q0 = src[0], q1 = src[1], q2 = src[2];
                const float s0 = q0.x;
                const float s1 = s0 + q0.y;
                const float s2 = s1 + q1.x;
                const float s3 = s2 + q1.y;
                const float s4 = s3 + q2.x;
                const float s5 = s4 + q2.y;
                float ss = s5;
                #pragma unroll
                for (int d = 1; d < 64; d <<= 1) {
                    float t = __shfl_up(ss, d);
                    if (lane >= d) ss += t;
                }
                const float base = ss - s5;
                float2* dst = (float2*)&lds[r][16 + x0];
                dst[0] = make_float2(base + s0, base + s1);
                dst[1] = make_float2(base + s2, base + s3);
                dst[2] = make_float2(base + s4, base + s5);
            }
        }
    }
    __syncthreads();

    // phase 2: column prefix via registers (independent reads, reg chain)
    {
        const int c = 16 + tid;            // tid in [0,384): every column
        float v[BAND];
        #pragma unroll
        for (int r = 0; r < BAND; ++r) v[r] = lds[r][c];
        float acc = 0.0f;
        #pragma unroll
        for (int r = 0; r < BAND; ++r) { acc += v[r]; v[r] = acc; }
        #pragma unroll
        for (int r = 0; r < BAND; ++r) lds[r][c] = v[r];
    }
    __syncthreads();

    // phase 3: right pads = S[r][383] (col 399) replicated to cols 400..415
    if (tid < 256) {
        const int r = tid >> 4, j = tid & 15;
        lds[r][400 + j] = lds[r][399];
    }
    __syncthreads();

    // phase 4: V taps + half2 store. thread -> (col pair, row half)
    {
        const int cp = tid % 192;          // col pair: cols 2cp, 2cp+1
        const int hf = tid / 192;          // rows hf*8 .. hf*8+7
        const int c0 = 16 + 2 * cp;
        const size_t obase = (size_t)b * NPIX + (size_t)y0 * W + 2 * cp;
        #pragma unroll
        for (int rr = 0; rr < 8; ++rr) {
            const int r = hf * 8 + rr;
            const float* R = lds[r];
            const __half2 h3  = __floats2half2_rn(R[c0+1]  - R[c0-2],  R[c0+2]  - R[c0-1]);
            const __half2 h15 = __floats2half2_rn(R[c0+7]  - R[c0-8],  R[c0+8]  - R[c0-7]);
            const __half2 h31 = __floats2half2_rn(R[c0+15] - R[c0-16], R[c0+16] - R[c0-15]);
            const size_t o = obase + (size_t)r * W;
            *(__half2*)(V3  + o) = h3;
            *(__half2*)(V15 + o) = h15;
            *(__half2*)(V31 + o) = h31;
        }
    }
}

// ---------------------------------------------------------------------------
// K2: fused loss (R12 hot loop). 4 cols/lane; 10 dwordx2 V taps + 2 float4
// per 256-px wave-iter; log2-domain BCE; SoA partials store. Branchless
// flag-multiplies for crossing taps (conditional loads regressed: divergent
// yo in it=1 made the "uniform" branches exec-masked -- R18 lesson).
// ---------------------------------------------------------------------------
struct __align__(8) H4 { __half2 a, b; };

__device__ inline void h4f(const H4 h, float o[4]) {
    const float2 fa = __half22float2(h.a);
    const float2 fb = __half22float2(h.b);
    o[0] = fa.x; o[1] = fa.y; o[2] = fb.x; o[3] = fb.y;
}

__global__ __launch_bounds__(256) void loss_kernel(
    const float* __restrict__ pred, const float* __restrict__ mask,
    const __half* __restrict__ V3, const __half* __restrict__ V15,
    const __half* __restrict__ V31, float* __restrict__ partials)
{
    const int tid  = threadIdx.x;
    const int wave = tid >> 6;
    const int lane = tid & 63;
    const int bid  = blockIdx.x;
    const int j    = bid >> 3;                    // 0..191
    const int b    = (bid & 7) + 8 * (j / CGPI);  // img%8 == XCD
    const int cg   = j % CGPI;                    // 0..47
    const int chunk = cg * 4 + wave;              // rows [2*chunk, 2*chunk+2)

    const size_t ibase = (size_t)b * NPIX;
    const float* mimg = mask + ibase;
    const float* pimg = pred + ibase;

    float pw = 0.f, pin = 0.f, pun = 0.f, pb = 0.f, pm = 0.f;
    // 0.5 folded into the box reciprocals (|b*k - m|*0.5 == |b*(k/2) - m/2|)
    const float i9h = 0.5f/9.0f, i225h = 0.5f/225.0f, i961h = 0.5f/961.0f;

    #pragma unroll
    for (int it = 0; it < ITERS; ++it) {
        const int q  = it * 256 + (lane << 2);    // 0..764
        const int yo = (q >= 384) ? 1 : 0;
        const int y  = (chunk << 1) + yo;
        const int x  = q - (yo ? 384 : 0);        // multiple of 4
        const size_t po = (size_t)chunk * 768 + q;

        const __half* v3x  = V3  + ibase + x;
        const __half* v15x = V15 + ibase + x;
        const __half* v31x = V31 + ibase + x;

        // ---- addresses & flags -------------------------------------------
        const int y1a  = min(y + 1, H - 1);
        const int yloa = y - 2;
        const int y0a  = yloa < 0 ? 0 : yloa;
        const int yta  = y0a | (BAND - 1);
        const float fLoA = yloa >= 0 ? 1.0f : 0.0f;
        const float fCA  = (yloa >= 0 && (y0a >> 4) != (y1a >> 4)) ? 1.0f : 0.0f;

        const int y1b  = min(y + 7, H - 1);
        const int ylob = y - 8;
        const int y0b  = ylob < 0 ? 0 : ylob;
        const int ytb  = y0b | (BAND - 1);
        const float fLoB = ylob >= 0 ? 1.0f : 0.0f;
        const float fCB  = (ylob >= 0 && (y0b >> 4) != (y1b >> 4)) ? 1.0f : 0.0f;

        const int y1c  = min(y + 15, H - 1);
        const int yloc = y - 16;
        const int y0c  = yloc < 0 ? 0 : yloc;
        const int sc   = yloc >= 0 ? (y0c >> 4) : 0;
        const int nc   = (y1c >> 4) - sc;
        const int rt1  = sc * BAND + (BAND - 1);
        const int rt2  = min(rt1 + BAND, H - 1);
        const float fLoC = yloc >= 0 ? 1.0f : 0.0f;
        const float g1   = nc >= 1 ? 1.0f : 0.0f;
        const float g2   = nc >= 2 ? 1.0f : 0.0f;

        // ---- loads -------------------------------------------------------
        const H4 A1 = *(const H4*)(v3x  + (size_t)y1a * W);
        const H4 A0 = *(const H4*)(v3x  + (size_t)y0a * W);
        const H4 AT = *(const H4*)(v3x  + (size_t)yta * W);
        const H4 B1 = *(const H4*)(v15x + (size_t)y1b * W);
        const H4 B0 = *(const H4*)(v15x + (size_t)y0b * W);
        const H4 BT = *(const H4*)(v15x + (size_t)ytb * W);
        const H4 C1 = *(const H4*)(v31x + (size_t)y1c * W);
        const H4 C0 = *(const H4*)(v31x + (size_t)y0c * W);
        const H4 T1 = *(const H4*)(v31x + (size_t)rt1 * W);
        const H4 T2 = *(const H4*)(v31x + (size_t)rt2 * W);
        const float4 mv = *(const float4*)(mimg + po);
        const float4 pv = *(const float4*)(pimg + po);

        // ---- convert + combine + loss ------------------------------------
        float a1[4], a0[4], at[4], b1[4], b0[4], bt[4], c1[4], c0[4], t1[4], t2[4];
        h4f(A1, a1); h4f(A0, a0); h4f(AT, at);
        h4f(B1, b1); h4f(B0, b0); h4f(BT, bt);
        h4f(C1, c1); h4f(C0, c0); h4f(T1, t1); h4f(T2, t2);

        const float mm[4] = { mv.x, mv.y, mv.z, mv.w };
        const float pp[4] = { pv.x, pv.y, pv.z, pv.w };

        #pragma unroll
        for (int c = 0; c < 4; ++c) {
            const float b3v  = a1[c] - fLoA * a0[c] + fCA * at[c];
            const float b15v = b1[c] - fLoB * b0[c] + fCB * bt[c];
            const float b31v = c1[c] - fLoC * c0[c] + g1 * t1[c] + g2 * t2[c];

            const float m = mm[c], p = pp[c];
            const float hm = 0.5f * m;
            const float t3  = fmaf(b3v,  i9h,   -hm);
            const float t15 = fmaf(b15v, i225h, -hm);
            const float t31 = fmaf(b31v, i961h, -hm);
            const float wh  = fabsf(t3) + fabsf(t15) + fabsf(t31);  // 0.5*w
            const float weit = fmaf(wh, m, 1.0f);                   // 1 + 0.5*w*m
            pw  += weit;
            pin  = fmaf(p * m, weit, pin);
            pun  = fmaf(p + m, weit, pun);
            const float lp = __log2f(p);
            const float lq = __log2f(1.0f - p);
            pb  -= fmaf(m, lp - lq, lq);     // = m*log2(p) + (1-m)*log2(1-p)
            pm  += fabsf(p - m);
        }
    }

    // deterministic wave butterfly
    #pragma unroll
    for (int off = 32; off >= 1; off >>= 1) {
        pw  += __shfl_xor(pw,  off);
        pin += __shfl_xor(pin, off);
        pun += __shfl_xor(pun, off);
        pb  += __shfl_xor(pb,  off);
        pm  += __shfl_xor(pm,  off);
    }
    __shared__ float red[4][5];
    if (lane == 0) {
        red[wave][0]=pw; red[wave][1]=pin; red[wave][2]=pun; red[wave][3]=pb; red[wave][4]=pm;
    }
    __syncthreads();
    if (tid == 0) {
        const int idx = b * CGPI + cg;               // 0..1535
        partials[0*NBLK2 + idx] = red[0][0]+red[1][0]+red[2][0]+red[3][0];
        partials[1*NBLK2 + idx] = red[0][1]+red[1][1]+red[2][1]+red[3][1];
        partials[2*NBLK2 + idx] = red[0][2]+red[1][2]+red[2][2]+red[3][2];
        partials[3*NBLK2 + idx] = red[0][3]+red[1][3]+red[2][3]+red[3][3];
        partials[4*NBLK2 + idx] = red[0][4]+red[1][4]+red[2][4]+red[3][4];
    }
}

// ---------------------------------------------------------------------------
// K3: finalize. 256 threads, fp64, fixed order -> deterministic scalar.
// SoA partials -> lane-coalesced loads (2 lines/instr vs 16-line gathers).
// ---------------------------------------------------------------------------
__global__ __launch_bounds__(256) void finalize_kernel(
    const float* __restrict__ partials, float* __restrict__ out)
{
    __shared__ double sB[4], sM[4];
    __shared__ double sw_[NB], si_[NB], su_[NB];

    const int tid = threadIdx.x;
    const int i   = tid >> 3;                 // image 0..31
    const int s   = tid & 7;

    // global bce/mae sums: fully coalesced (plane 3 and 4)
    double Bc = 0, Ma = 0;
    #pragma unroll
    for (int jj = 0; jj < NBLK2 / 256; ++jj) {
        Bc += (double)partials[3*NBLK2 + tid + 256*jj];
        Ma += (double)partials[4*NBLK2 + tid + 256*jj];
    }
    // per-image sums: 8 lanes per image, consecutive k within group
    double Sw = 0, Si = 0, Su = 0;
    #pragma unroll
    for (int jj = 0; jj < CGPI / 8; ++jj) {
        const int k = i * CGPI + s + 8*jj;
        Sw += (double)partials[0*NBLK2 + k];
        Si += (double)partials[1*NBLK2 + k];
        Su += (double)partials[2*NBLK2 + k];
    }
    #pragma unroll
    for (int d = 4; d >= 1; d >>= 1) {
        Sw += __shfl_down(Sw, d);
        Si += __shfl_down(Si, d);
        Su += __shfl_down(Su, d);
    }
    if (s == 0) { sw_[i] = Sw; si_[i] = Si; su_[i] = Su; }
    #pragma unroll
    for (int d = 32; d >= 1; d >>= 1) {
        Bc += __shfl_down(Bc, d);
        Ma += __shfl_down(Ma, d);
    }
    if ((tid & 63) == 0) { sB[tid >> 6] = Bc; sM[tid >> 6] = Ma; }
    __syncthreads();

    if (tid < 64) {
        double wiou = 0.0, ratio = 0.0;
        if (tid < NB) {
            const double w = sw_[tid], ii = si_[tid], u = su_[tid];
            wiou  = 1.0 - ii / (u - ii);
            ratio = w / (w - (double)NPIX);
        }
        #pragma unroll
        for (int d = 32; d >= 1; d >>= 1) {
            wiou  += __shfl_down(wiou,  d);
            ratio += __shfl_down(ratio, d);
        }
        if (tid == 0) {
            const double bt  = (sB[0] + sB[1] + sB[2] + sB[3]) * 0.6931471805599453; // ln2
            const double mt  = sM[0] + sM[1] + sM[2] + sM[3];
            const double tot = (double)NB * (double)NPIX;
            const double bce = bt / tot;
            const double mae = mt / tot;
            out[0] = (float)(0.7 * (bce + wiou / (double)NB + mae * ratio / (double)NB));
        }
    }
}

extern "C" void kernel_launch(void* const* d_in, const int* in_sizes, int n_in,
                              void* d_out, int out_size, void* d_ws, size_t ws_size,
                              hipStream_t stream) {
    const float* pred = (const float*)d_in[0];
    const float* mask = (const float*)d_in[1];
    float* out        = (float*)d_out;

    // ws layout: V3 | V15 | V31 (each 32*384*384 fp16 = 4.72 MB) | partials(SoA)
    const size_t vplane = (size_t)NB * NPIX;           // elements
    __half* V3  = (__half*)d_ws;
    __half* V15 = V3  + vplane;
    __half* V31 = V15 + vplane;
    float* partials = (float*)(V31 + vplane);          // 5*1536*4 = 30 KB

    band_v_kernel<<<dim3(NBLK1), dim3(384), 0, stream>>>(mask, V3, V15, V31);
    loss_kernel<<<dim3(NBLK2), dim3(256), 0, stream>>>(pred, mask, V3, V15, V31, partials);
    finalize_kernel<<<dim3(1), dim3(256), 0, stream>>>(partials, out);
}